// Round 5
// baseline (467.985 us; speedup 1.0000x reference)
//
#include <hip/hip_runtime.h>

#define Bc   2
#define Cc   256
#define Hc   200
#define Wc   200
#define NROI 512
#define NBIN 49
#define HWn  (Hc * Wc)                 // 40000
#define NHWT ((HWn + 63) / 64)         // 625 hw-tiles of 64 positions
#define NTILE (NHWT * 8)               // 5000 = hwt*8 + ctile*2 + batch
#define NPROD 512                      // producer blocks
#define NPASS ((NTILE + NPROD - 1) / NPROD)   // 10
#define NCONS (NROI * 2)               // consumer blocks (2 per roi)
#define LSTRIDE 260                    // sbuf row stride (floats)
#define MAP_BYTES ((size_t)Bc * HWn * Cc * 2) // 40,960,000 bf16 NHWC map

// ---- bf16 helpers (RNE) ----
__device__ inline unsigned short f2bf(float f) {
    unsigned int u = __float_as_uint(f);
    return (unsigned short)((u + 0x7FFFu + ((u >> 16) & 1u)) >> 16);
}
__device__ inline float bf2f(unsigned short u) {
    return __uint_as_float(((unsigned int)u) << 16);
}

struct RoiParams { int b; float cx, cy, rw, rh, cs, sn, bh, bw; };

__device__ inline RoiParams load_roi(const float* rois, int n) {
    RoiParams p;
    const float* r = rois + n * 6;
    p.b  = (int)r[0];
    p.cx = r[1] * 0.25f;  p.cy = r[2] * 0.25f;
    p.rw = fmaxf(r[3] * 0.25f, 1.0f);
    p.rh = fmaxf(r[4] * 0.25f, 1.0f);
    p.cs = cosf(r[5]);    p.sn = sinf(r[5]);
    p.bh = p.rh * (1.0f / 7.0f);
    p.bw = p.rw * (1.0f / 7.0f);
    return p;
}

// per-sample coords -> 4 (weight, pixel) pairs; validity+mean folded into weights
__device__ inline void sample_wix(const RoiParams& p, int ph, int pw, int s,
                                  float* wt, int* pix) {
    const float sy = (s >> 1) ? 0.75f : 0.25f;
    const float sx = (s & 1)  ? 0.75f : 0.25f;
    const float yy = -0.5f * p.rh + ((float)ph + sy) * p.bh;
    const float xx = -0.5f * p.rw + ((float)pw + sx) * p.bw;
    float y = yy * p.cs - xx * p.sn + p.cy;
    float x = yy * p.sn + xx * p.cs + p.cx;
    const bool valid = (y > -1.0f) && (y < (float)Hc) && (x > -1.0f) && (x < (float)Wc);
    y = fmaxf(y, 0.0f); x = fmaxf(x, 0.0f);
    int yl = (int)y, xl = (int)x;
    const bool hiy = yl >= Hc - 1, hix = xl >= Wc - 1;
    yl = min(yl, Hc - 1); xl = min(xl, Wc - 1);
    const int yh = hiy ? (Hc - 1) : (yl + 1);
    const int xh = hix ? (Wc - 1) : (xl + 1);
    const float ly = hiy ? 0.0f : (y - (float)yl);
    const float lx = hix ? 0.0f : (x - (float)xl);
    const float hy = 1.0f - ly, hx = 1.0f - lx;
    const float vm = valid ? 0.25f : 0.0f;
    wt[0] = vm * hy * hx;  wt[1] = vm * hy * lx;
    wt[2] = vm * ly * hx;  wt[3] = vm * ly * lx;
    const int rl = (p.b * Hc + yl) * Wc;
    const int rt = (p.b * Hc + yh) * Wc;
    pix[0] = rl + xl;  pix[1] = rl + xh;
    pix[2] = rt + xl;  pix[3] = rt + xh;
}

// ---- consumer: NHWC bf16 gather for NB bins starting at B0 ----
template <int NB, int B0>
__device__ void consume_bins(const ushort4* __restrict__ f4, const RoiParams& p,
                             float* sbuf, int t) {
    const int w = t >> 6, cq = t & 63;
    for (int bl = w; bl < NB; bl += 4) {
        const int bin = B0 + bl;
        const int ph = bin / 7, pw = bin - ph * 7;
        float a0 = 0.f, a1 = 0.f, a2 = 0.f, a3 = 0.f;
        #pragma unroll
        for (int g = 0; g < 2; ++g) {
            float wt[8]; int ix[8];
            #pragma unroll
            for (int si = 0; si < 2; ++si) {
                float wts[4]; int pix[4];
                sample_wix(p, ph, pw, g * 2 + si, wts, pix);
                #pragma unroll
                for (int k = 0; k < 4; ++k) {
                    wt[si * 4 + k] = wts[k];
                    ix[si * 4 + k] = pix[k] * 64 + cq;
                }
            }
            ushort4 v[8];
            #pragma unroll
            for (int i = 0; i < 8; ++i) v[i] = f4[ix[i]];
            #pragma unroll
            for (int i = 0; i < 8; ++i) {
                a0 += wt[i] * bf2f(v[i].x);
                a1 += wt[i] * bf2f(v[i].y);
                a2 += wt[i] * bf2f(v[i].z);
                a3 += wt[i] * bf2f(v[i].w);
            }
        }
        float4 res; res.x = a0; res.y = a1; res.z = a2; res.w = a3;
        *(float4*)(&sbuf[bl * LSTRIDE + cq * 4]) = res;
    }
}

// ---- consumer fallback: NCHW fp32 gather (only on spin timeout; always correct) ----
template <int NB, int B0>
__device__ void consume_nchw(const float* __restrict__ in, const RoiParams& p,
                             float* sbuf, int t) {
    const int w = t >> 6, cq = t & 63;
    for (int bl = w; bl < NB; bl += 4) {
        const int bin = B0 + bl;
        const int ph = bin / 7, pw = bin - ph * 7;
        float acc[4] = {0.f, 0.f, 0.f, 0.f};
        for (int s = 0; s < 4; ++s) {
            float wts[4]; int pix[4];
            sample_wix(p, ph, pw, s, wts, pix);
            const size_t base = (size_t)(p.b * Cc + cq * 4) * HWn - (size_t)p.b * Hc * Wc;
            // pix already includes batch row offset (p.b*Hc*Wc); base removes it for NCHW
            #pragma unroll
            for (int i = 0; i < 4; ++i) {
                const size_t cb = (size_t)(p.b * Cc + cq * 4 + i) * HWn;
                const int local0 = pix[0] - p.b * HWn, local1 = pix[1] - p.b * HWn;
                const int local2 = pix[2] - p.b * HWn, local3 = pix[3] - p.b * HWn;
                acc[i] += wts[0] * in[cb + local0] + wts[1] * in[cb + local1] +
                          wts[2] * in[cb + local2] + wts[3] * in[cb + local3];
            }
        }
        #pragma unroll
        for (int i = 0; i < 4; ++i) sbuf[bl * LSTRIDE + cq * 4 + i] = acc[i];
    }
}

template <int NB, int B0>
__device__ void writeout(float* __restrict__ out, const float* sbuf, int n, int t) {
    const size_t obase = (size_t)n * (Cc * NBIN);
    for (int e = t; e < Cc * NB; e += 256) {
        const int c  = e / NB;
        const int bi = e - c * NB;
        out[obase + (size_t)c * NBIN + B0 + bi] = sbuf[bi * LSTRIDE + c];
    }
}

// ---------------- fused producer/consumer kernel ----------------
__global__ __launch_bounds__(256, 6) void fused_roialign(const float* __restrict__ in,
                                                         const float* __restrict__ rois,
                                                         float* __restrict__ out,
                                                         unsigned short* __restrict__ map,
                                                         unsigned int* __restrict__ cnt) {
    __shared__ union {
        unsigned short tile[64][65];   // producer transpose tile
        float sbuf[25 * LSTRIDE];      // consumer staging
    } sh;
    __shared__ int s_ok;

    const int bid = blockIdx.x;
    const int t   = threadIdx.x;

    if (bid < NPROD) {
        // ---- producer: transpose tiles in hw-order, publish per-pass counters ----
        for (int pass = 0; pass < NPASS; ++pass) {
            const int slot = pass * NPROD + bid;
            const bool active = slot < NTILE;
            int hw0 = 0, c0 = 0, bb = 0;
            if (active) {
                const int hwt = slot >> 3, rem = slot & 7;
                c0 = (rem >> 1) * 64; bb = rem & 1; hw0 = hwt * 64;
            }
            if (active) {
                const int tx = t & 63, ty = t >> 6;
                #pragma unroll
                for (int i = ty; i < 64; i += 4)
                    sh.tile[i][tx] = f2bf(in[(size_t)(bb * Cc + c0 + i) * HWn + hw0 + tx]);
            }
            __syncthreads();
            if (active) {
                const int j = t & 31, r0 = t >> 5;
                unsigned int* m32 = (unsigned int*)map;
                #pragma unroll
                for (int r = r0; r < 64; r += 8) {
                    unsigned int lo = sh.tile[2 * j][r];
                    unsigned int hi = sh.tile[2 * j + 1][r];
                    unsigned int* dst = m32 + (((size_t)(bb * HWn + hw0 + r) * Cc + c0) >> 1) + j;
                    // agent-scope store: visible cross-XCD within this dispatch
                    __hip_atomic_store(dst, lo | (hi << 16), __ATOMIC_RELAXED,
                                       __HIP_MEMORY_SCOPE_AGENT);
                }
            }
            __syncthreads();   // vmcnt(0) drain: data ack'd before counter bump
            if (t == 0)
                __hip_atomic_fetch_add(&cnt[pass], 1u, __ATOMIC_RELAXED,
                                       __HIP_MEMORY_SCOPE_AGENT);
        }
        return;
    }

    // ---- consumer: 2 blocks per roi ----
    const int cid  = bid - NPROD;
    const int n    = cid >> 1;
    const int half = cid & 1;
    const RoiParams p = load_roi(rois, n);

    // highest image row this roi can touch (+2 rows fp-slack)
    const float dyext = 0.5f * (p.rh * fabsf(p.cs) + p.rw * fabsf(p.sn));
    int rhi = (int)floorf(p.cy + dyext) + 2;
    rhi = min(max(rhi, 0), Hc - 1);
    const int hwtmax = (rhi * Wc + (Wc - 1)) >> 6;
    const int P = ((hwtmax << 3) + 7) >> 9;   // pass index whose completion covers us

    if (t == 0) {
        int budget = 50000;
        while (__hip_atomic_load(&cnt[P], __ATOMIC_RELAXED, __HIP_MEMORY_SCOPE_AGENT)
               < (unsigned int)NPROD) {
            __builtin_amdgcn_s_sleep(16);
            if (--budget <= 0) break;
        }
        s_ok = (budget > 0) ? 1 : 0;
    }
    __syncthreads();
    const bool ok = (s_ok != 0);

    if (ok) {
        const ushort4* f4 = (const ushort4*)map;
        if (half == 0) consume_bins<24, 0>(f4, p, sh.sbuf, t);
        else           consume_bins<25, 24>(f4, p, sh.sbuf, t);
    } else {
        if (half == 0) consume_nchw<24, 0>(in, p, sh.sbuf, t);
        else           consume_nchw<25, 24>(in, p, sh.sbuf, t);
    }
    __syncthreads();
    if (half == 0) writeout<24, 0>(out, sh.sbuf, n, t);
    else           writeout<25, 24>(out, sh.sbuf, n, t);
}

// ---------------- legacy NCHW fp32 kernel (only if ws too small) ----------------
__global__ __launch_bounds__(256) void roialign_nchw(const float* __restrict__ feat,
                                                     const float* __restrict__ rois,
                                                     float* __restrict__ out) {
    __shared__ float sbuf[NBIN * LSTRIDE];
    const int n = blockIdx.x, t = threadIdx.x;
    const int g = t >> 6, cq = t & 63;
    const RoiParams p = load_roi(rois, n);
    for (int bin = g; bin < NBIN; bin += 4) {
        const int ph = bin / 7, pw = bin - ph * 7;
        float acc[4] = {0.f, 0.f, 0.f, 0.f};
        for (int s = 0; s < 4; ++s) {
            float wts[4]; int pix[4];
            sample_wix(p, ph, pw, s, wts, pix);
            #pragma unroll
            for (int i = 0; i < 4; ++i) {
                const size_t cb = (size_t)(p.b * Cc + cq * 4 + i) * HWn;
                acc[i] += wts[0] * feat[cb + pix[0] - p.b * HWn] +
                          wts[1] * feat[cb + pix[1] - p.b * HWn] +
                          wts[2] * feat[cb + pix[2] - p.b * HWn] +
                          wts[3] * feat[cb + pix[3] - p.b * HWn];
            }
        }
        #pragma unroll
        for (int i = 0; i < 4; ++i) sbuf[bin * LSTRIDE + cq * 4 + i] = acc[i];
    }
    __syncthreads();
    const size_t obase = (size_t)n * (Cc * NBIN);
    for (int e = t; e < Cc * NBIN; e += 256) {
        const int c = e / NBIN, bi = e - c * NBIN;
        out[obase + e] = sbuf[bi * LSTRIDE + c];
    }
}

extern "C" void kernel_launch(void* const* d_in, const int* in_sizes, int n_in,
                              void* d_out, int out_size, void* d_ws, size_t ws_size,
                              hipStream_t stream) {
    const float* inputs = (const float*)d_in[0];
    const float* rois   = (const float*)d_in[1];
    float* out = (float*)d_out;

    const size_t need = MAP_BYTES + 64;
    if (d_ws != nullptr && ws_size >= need) {
        unsigned short* map = (unsigned short*)d_ws;
        unsigned int* cnt = (unsigned int*)((char*)d_ws + MAP_BYTES);
        hipMemsetAsync(cnt, 0, 64, stream);
        fused_roialign<<<NPROD + NCONS, 256, 0, stream>>>(inputs, rois, out, map, cnt);
    } else {
        roialign_nchw<<<NROI, 256, 0, stream>>>(inputs, rois, out);
    }
}

// Round 6
// 63.761 us; speedup vs baseline: 7.3397x; 7.3397x over previous
//
#include <hip/hip_runtime.h>

#define Bc   2
#define Cc   256
#define Hc   200
#define Wc   200
#define NROI 512
#define NBIN 49
#define HWn  (Hc * Wc)
#define LSTRIDE 260   // floats; 49*260*4 = 50,960 B LDS

using u16x8 = __attribute__((ext_vector_type(8))) unsigned short;  // 16 B

// ---- bf16 helpers (RNE) ----
__device__ inline unsigned short f2bf(float f) {
    unsigned int u = __float_as_uint(f);
    return (unsigned short)((u + 0x7FFFu + ((u >> 16) & 1u)) >> 16);
}
__device__ inline float bf2f(unsigned short u) {
    return __uint_as_float(((unsigned int)u) << 16);
}

struct RoiParams { int b; float cx, cy, rw, rh, cs, sn, bh, bw; };

__device__ inline RoiParams load_roi(const float* rois, int n) {
    RoiParams p;
    const float* r = rois + n * 6;
    p.b  = (int)r[0];
    p.cx = r[1] * 0.25f;  p.cy = r[2] * 0.25f;
    p.rw = fmaxf(r[3] * 0.25f, 1.0f);
    p.rh = fmaxf(r[4] * 0.25f, 1.0f);
    p.cs = cosf(r[5]);    p.sn = sinf(r[5]);
    p.bh = p.rh * (1.0f / 7.0f);
    p.bw = p.rw * (1.0f / 7.0f);
    return p;
}

// per-sample coords -> 4 corner weights (validity+mean folded) + 4 pixel indices
__device__ inline void sample_wix(const RoiParams& p, int ph, int pw, int s,
                                  float* wt, int* pix) {
    const float sy = (s >> 1) ? 0.75f : 0.25f;
    const float sx = (s & 1)  ? 0.75f : 0.25f;
    const float yy = -0.5f * p.rh + ((float)ph + sy) * p.bh;
    const float xx = -0.5f * p.rw + ((float)pw + sx) * p.bw;
    float y = yy * p.cs - xx * p.sn + p.cy;
    float x = yy * p.sn + xx * p.cs + p.cx;
    const bool valid = (y > -1.0f) && (y < (float)Hc) && (x > -1.0f) && (x < (float)Wc);
    y = fmaxf(y, 0.0f); x = fmaxf(x, 0.0f);
    int yl = (int)y, xl = (int)x;
    const bool hiy = yl >= Hc - 1, hix = xl >= Wc - 1;
    yl = min(yl, Hc - 1); xl = min(xl, Wc - 1);
    const int yh = hiy ? (Hc - 1) : (yl + 1);
    const int xh = hix ? (Wc - 1) : (xl + 1);
    const float ly = hiy ? 0.0f : (y - (float)yl);
    const float lx = hix ? 0.0f : (x - (float)xl);
    const float hy = 1.0f - ly, hx = 1.0f - lx;
    const float vm = valid ? 0.25f : 0.0f;
    wt[0] = vm * hy * hx;  wt[1] = vm * hy * lx;
    wt[2] = vm * ly * hx;  wt[3] = vm * ly * lx;
    const int rl = (p.b * Hc + yl) * Wc;
    const int rt = (p.b * Hc + yh) * Wc;
    pix[0] = rl + xl;  pix[1] = rl + xh;
    pix[2] = rt + xl;  pix[3] = rt + xh;
}

// ---------------- NCHW fp32 -> NHWC bf16 transpose (64x64 LDS tile) ----------------
__global__ __launch_bounds__(256) void transpose_to_bf16_nhwc(const float* __restrict__ in,
                                                              unsigned short* __restrict__ out) {
    __shared__ unsigned short tile[64][65];
    const int b   = blockIdx.z;
    const int hw0 = blockIdx.x * 64;
    const int c0  = blockIdx.y * 64;
    const int tx  = threadIdx.x & 63;
    const int ty  = threadIdx.x >> 6;

    #pragma unroll
    for (int i = ty; i < 64; i += 4) {
        float v = in[(size_t)(b * Cc + c0 + i) * HWn + hw0 + tx];
        tile[i][tx] = f2bf(v);   // channel = c0+i, hw = hw0+tx
    }
    __syncthreads();

    const int j  = threadIdx.x & 31;    // channel pair -> c0+2j, c0+2j+1
    const int r0 = threadIdx.x >> 5;    // 0..7
    unsigned int* out32 = (unsigned int*)out;
    #pragma unroll
    for (int r = r0; r < 64; r += 8) {
        unsigned int lo = tile[2 * j][r];
        unsigned int hi = tile[2 * j + 1][r];
        out32[((size_t)(b * HWn + hw0 + r) * Cc + c0) / 2 + j] = lo | (hi << 16);
    }
}

// ---------------- main kernel: 16B/lane paired-corner gathers ----------------
// One block (512 thr = 8 waves) per roi; wave w handles bins w, w+8, ...
// Lane split: c2 = lane>>5 (corner-half), ch8 = lane&31 (8 channels as ushort8).
// Per sample: 2 wave-loads fetch all 4 corners x 256 ch (1 KB/instr).
// Final cross-half merge via __shfl_xor(.,32); lanes 0..31 stage to LDS.
__global__ __launch_bounds__(512, 4) void roialign_bf16(const unsigned short* __restrict__ feat,
                                                        const float* __restrict__ rois,
                                                        float* __restrict__ out) {
    __shared__ float sbuf[NBIN * LSTRIDE];

    const int n   = blockIdx.x;
    const int t   = threadIdx.x;
    const int w   = t >> 6;
    const int c2  = (t >> 5) & 1;   // corner-half: corners c2 and c2+2
    const int ch8 = t & 31;         // channels ch8*8 .. ch8*8+7

    const RoiParams p = load_roi(rois, n);
    const u16x8* f8 = (const u16x8*)feat;   // 32 groups of 8 channels per pixel

    for (int bin = w; bin < NBIN; bin += 8) {
        const int ph = bin / 7;
        const int pw = bin - ph * 7;

        float wt[16];
        int   pix[16];
        #pragma unroll
        for (int s = 0; s < 4; ++s)
            sample_wix(p, ph, pw, s, &wt[s * 4], &pix[s * 4]);

        // 8 back-to-back wave-loads (2 per sample)
        u16x8 v[8];
        #pragma unroll
        for (int s = 0; s < 4; ++s) {
            v[s * 2 + 0] = f8[pix[s * 4 + c2]     * 32 + ch8];   // corner c2
            v[s * 2 + 1] = f8[pix[s * 4 + 2 + c2] * 32 + ch8];   // corner 2+c2
        }

        float acc[8] = {0.f, 0.f, 0.f, 0.f, 0.f, 0.f, 0.f, 0.f};
        #pragma unroll
        for (int s = 0; s < 4; ++s) {
            const float w0 = wt[s * 4 + c2];
            const float w1 = wt[s * 4 + 2 + c2];
            #pragma unroll
            for (int j = 0; j < 8; ++j)
                acc[j] += w0 * bf2f(v[s * 2 + 0][j]) + w1 * bf2f(v[s * 2 + 1][j]);
        }

        // merge corner halves: lane l + lane l^32
        #pragma unroll
        for (int j = 0; j < 8; ++j)
            acc[j] += __shfl_xor(acc[j], 32, 64);

        if (c2 == 0) {
            float4 r0, r1;
            r0.x = acc[0]; r0.y = acc[1]; r0.z = acc[2]; r0.w = acc[3];
            r1.x = acc[4]; r1.y = acc[5]; r1.z = acc[6]; r1.w = acc[7];
            *(float4*)(&sbuf[bin * LSTRIDE + ch8 * 8 + 0]) = r0;
            *(float4*)(&sbuf[bin * LSTRIDE + ch8 * 8 + 4]) = r1;
        }
    }

    __syncthreads();

    // coalesced writeout: out[n][c][ph][pw], flat e = c*49 + bin
    const size_t obase = (size_t)n * (Cc * NBIN);
    for (int e = t; e < Cc * NBIN; e += 512) {
        const int c  = e / NBIN;
        const int bi = e - c * NBIN;
        out[obase + e] = sbuf[bi * LSTRIDE + c];
    }
}

// ---------------- fp32 NCHW fallback (only if ws too small) ----------------
__global__ __launch_bounds__(256) void roialign_nchw(const float* __restrict__ feat,
                                                     const float* __restrict__ rois,
                                                     float* __restrict__ out) {
    __shared__ float sbuf[NBIN * LSTRIDE];
    const int n = blockIdx.x, t = threadIdx.x;
    const int g = t >> 6, cq = t & 63;
    const RoiParams p = load_roi(rois, n);
    for (int bin = g; bin < NBIN; bin += 4) {
        const int ph = bin / 7, pw = bin - ph * 7;
        float acc[4] = {0.f, 0.f, 0.f, 0.f};
        for (int s = 0; s < 4; ++s) {
            float wts[4]; int pix[4];
            sample_wix(p, ph, pw, s, wts, pix);
            #pragma unroll
            for (int i = 0; i < 4; ++i) {
                const size_t cb = (size_t)(p.b * Cc + cq * 4 + i) * HWn;
                acc[i] += wts[0] * feat[cb + pix[0] - p.b * HWn] +
                          wts[1] * feat[cb + pix[1] - p.b * HWn] +
                          wts[2] * feat[cb + pix[2] - p.b * HWn] +
                          wts[3] * feat[cb + pix[3] - p.b * HWn];
            }
        }
        #pragma unroll
        for (int i = 0; i < 4; ++i) sbuf[bin * LSTRIDE + cq * 4 + i] = acc[i];
    }
    __syncthreads();
    const size_t obase = (size_t)n * (Cc * NBIN);
    for (int e = t; e < Cc * NBIN; e += 256) {
        const int c = e / NBIN, bi = e - c * NBIN;
        out[obase + e] = sbuf[bi * LSTRIDE + c];
    }
}

extern "C" void kernel_launch(void* const* d_in, const int* in_sizes, int n_in,
                              void* d_out, int out_size, void* d_ws, size_t ws_size,
                              hipStream_t stream) {
    const float* inputs = (const float*)d_in[0];
    const float* rois   = (const float*)d_in[1];
    float* out = (float*)d_out;

    const size_t need = (size_t)Bc * HWn * Cc * sizeof(unsigned short);
    if (d_ws != nullptr && ws_size >= need) {
        unsigned short* nhwc = (unsigned short*)d_ws;
        dim3 tg(HWn / 64, Cc / 64, Bc);
        transpose_to_bf16_nhwc<<<tg, 256, 0, stream>>>(inputs, nhwc);
        roialign_bf16<<<NROI, 512, 0, stream>>>(nhwc, rois, out);
    } else {
        roialign_nchw<<<NROI, 256, 0, stream>>>(inputs, rois, out);
    }
}

// Round 7
// 48.110 us; speedup vs baseline: 9.7274x; 1.3253x over previous
//
#include <hip/hip_runtime.h>

#define Bc   2
#define Cc   256
#define Hc   200
#define Wc   200
#define NROI 512
#define NBIN 49
#define HWn  (Hc * Wc)
#define LSTRIDE 260   // floats; 13*260*4 = 13,520 B LDS in main kernel

// ---- bf16 helpers (RNE) ----
__device__ inline unsigned short f2bf(float f) {
    unsigned int u = __float_as_uint(f);
    return (unsigned short)((u + 0x7FFFu + ((u >> 16) & 1u)) >> 16);
}
__device__ inline float bf2f(unsigned short u) {
    return __uint_as_float(((unsigned int)u) << 16);
}

struct RoiParams { int b; float cx, cy, rw, rh, cs, sn, bh, bw; };

__device__ inline RoiParams load_roi(const float* rois, int n) {
    RoiParams p;
    const float* r = rois + n * 6;
    p.b  = (int)r[0];
    p.cx = r[1] * 0.25f;  p.cy = r[2] * 0.25f;
    p.rw = fmaxf(r[3] * 0.25f, 1.0f);
    p.rh = fmaxf(r[4] * 0.25f, 1.0f);
    p.cs = cosf(r[5]);    p.sn = sinf(r[5]);
    p.bh = p.rh * (1.0f / 7.0f);
    p.bw = p.rw * (1.0f / 7.0f);
    return p;
}

// per-sample coords -> 4 corner weights (validity+mean folded) + 4 pixel indices
__device__ inline void sample_wix(const RoiParams& p, int ph, int pw, int s,
                                  float* wt, int* pix) {
    const float sy = (s >> 1) ? 0.75f : 0.25f;
    const float sx = (s & 1)  ? 0.75f : 0.25f;
    const float yy = -0.5f * p.rh + ((float)ph + sy) * p.bh;
    const float xx = -0.5f * p.rw + ((float)pw + sx) * p.bw;
    float y = yy * p.cs - xx * p.sn + p.cy;
    float x = yy * p.sn + xx * p.cs + p.cx;
    const bool valid = (y > -1.0f) && (y < (float)Hc) && (x > -1.0f) && (x < (float)Wc);
    y = fmaxf(y, 0.0f); x = fmaxf(x, 0.0f);
    int yl = (int)y, xl = (int)x;
    const bool hiy = yl >= Hc - 1, hix = xl >= Wc - 1;
    yl = min(yl, Hc - 1); xl = min(xl, Wc - 1);
    const int yh = hiy ? (Hc - 1) : (yl + 1);
    const int xh = hix ? (Wc - 1) : (xl + 1);
    const float ly = hiy ? 0.0f : (y - (float)yl);
    const float lx = hix ? 0.0f : (x - (float)xl);
    const float hy = 1.0f - ly, hx = 1.0f - lx;
    const float vm = valid ? 0.25f : 0.0f;
    wt[0] = vm * hy * hx;  wt[1] = vm * hy * lx;
    wt[2] = vm * ly * hx;  wt[3] = vm * ly * lx;
    const int rl = (p.b * Hc + yl) * Wc;
    const int rt = (p.b * Hc + yh) * Wc;
    pix[0] = rl + xl;  pix[1] = rl + xh;
    pix[2] = rt + xl;  pix[3] = rt + xh;
}

// ---------------- NCHW fp32 -> NHWC bf16 transpose (64x64 LDS tile) ----------------
__global__ __launch_bounds__(256) void transpose_to_bf16_nhwc(const float* __restrict__ in,
                                                              unsigned short* __restrict__ out) {
    __shared__ unsigned short tile[64][65];
    const int b   = blockIdx.z;
    const int hw0 = blockIdx.x * 64;
    const int c0  = blockIdx.y * 64;
    const int tx  = threadIdx.x & 63;
    const int ty  = threadIdx.x >> 6;

    #pragma unroll
    for (int i = ty; i < 64; i += 4) {
        float v = in[(size_t)(b * Cc + c0 + i) * HWn + hw0 + tx];
        tile[i][tx] = f2bf(v);   // channel = c0+i, hw = hw0+tx
    }
    __syncthreads();

    const int j  = threadIdx.x & 31;    // channel pair -> c0+2j, c0+2j+1
    const int r0 = threadIdx.x >> 5;    // 0..7
    unsigned int* out32 = (unsigned int*)out;
    #pragma unroll
    for (int r = r0; r < 64; r += 8) {
        unsigned int lo = tile[2 * j][r];
        unsigned int hi = tile[2 * j + 1][r];
        out32[((size_t)(b * HWn + hw0 + r) * Cc + c0) / 2 + j] = lo | (hi << 16);
    }
}

// ---------------- main kernel: 4 blocks per roi, round-4 gather body ----------------
// 2048 blocks of 256 thr (4 waves). Block = (roi r, part j); part j owns bins
// [j*12, j*12+NB) with NB = 12,12,12,13. Wave w handles bins w, w+4, ... of the
// part; 64 lanes cover 256 channels as ushort4. Branchless; 16 corner loads of
// a bin issue back-to-back. Sibling blocks of a roi share an XCD (bid%8 = r%8).
template <int NB, int B0>
__device__ void consume_part(const ushort4* __restrict__ f4, const RoiParams& p,
                             float* sbuf, int t) {
    const int w  = t >> 6;
    const int cq = t & 63;
    for (int bl = w; bl < NB; bl += 4) {
        const int bin = B0 + bl;
        const int ph = bin / 7;
        const int pw = bin - ph * 7;

        float wt[16];
        int   ix[16];
        #pragma unroll
        for (int s = 0; s < 4; ++s) {
            float wts[4]; int pix[4];
            sample_wix(p, ph, pw, s, wts, pix);
            #pragma unroll
            for (int k = 0; k < 4; ++k) {
                wt[s * 4 + k] = wts[k];
                ix[s * 4 + k] = pix[k] * 64 + cq;
            }
        }

        ushort4 v[16];
        #pragma unroll
        for (int i = 0; i < 16; ++i) v[i] = f4[ix[i]];

        float ax = 0.f, ay = 0.f, az = 0.f, aw = 0.f;
        #pragma unroll
        for (int i = 0; i < 16; ++i) {
            ax += wt[i] * bf2f(v[i].x);
            ay += wt[i] * bf2f(v[i].y);
            az += wt[i] * bf2f(v[i].z);
            aw += wt[i] * bf2f(v[i].w);
        }

        float4 res; res.x = ax; res.y = ay; res.z = az; res.w = aw;
        *(float4*)(&sbuf[bl * LSTRIDE + cq * 4]) = res;
    }
}

template <int NB, int B0>
__device__ void writeout_part(float* __restrict__ out, const float* sbuf, int n, int t) {
    const size_t obase = (size_t)n * (Cc * NBIN);
    for (int e = t; e < Cc * NB; e += 256) {
        const int c  = e / NB;
        const int bi = e - c * NB;
        out[obase + (size_t)c * NBIN + B0 + bi] = sbuf[bi * LSTRIDE + c];
    }
}

__global__ __launch_bounds__(256, 4) void roialign_bf16(const unsigned short* __restrict__ feat,
                                                        const float* __restrict__ rois,
                                                        float* __restrict__ out) {
    __shared__ float sbuf[13 * LSTRIDE];

    // bid = (r&7) | (((r>>3)*4 + j) << 3)  -- bijective; siblings share bid%8 (XCD)
    const int bid = blockIdx.x;
    const int q   = bid >> 3;
    const int n   = ((q >> 2) << 3) | (bid & 7);   // roi index
    const int j   = q & 3;                         // part 0..3
    const int t   = threadIdx.x;

    const RoiParams p = load_roi(rois, n);
    const ushort4* f4 = (const ushort4*)feat;

    if (j == 0)      consume_part<12,  0>(f4, p, sbuf, t);
    else if (j == 1) consume_part<12, 12>(f4, p, sbuf, t);
    else if (j == 2) consume_part<12, 24>(f4, p, sbuf, t);
    else             consume_part<13, 36>(f4, p, sbuf, t);

    __syncthreads();

    if (j == 0)      writeout_part<12,  0>(out, sbuf, n, t);
    else if (j == 1) writeout_part<12, 12>(out, sbuf, n, t);
    else if (j == 2) writeout_part<12, 24>(out, sbuf, n, t);
    else             writeout_part<13, 36>(out, sbuf, n, t);
}

// ---------------- fp32 NCHW fallback (only if ws too small) ----------------
__global__ __launch_bounds__(256) void roialign_nchw(const float* __restrict__ feat,
                                                     const float* __restrict__ rois,
                                                     float* __restrict__ out) {
    __shared__ float sbuf[NBIN * LSTRIDE];
    const int n = blockIdx.x, t = threadIdx.x;
    const int g = t >> 6, cq = t & 63;
    const RoiParams p = load_roi(rois, n);
    for (int bin = g; bin < NBIN; bin += 4) {
        const int ph = bin / 7, pw = bin - ph * 7;
        float acc[4] = {0.f, 0.f, 0.f, 0.f};
        for (int s = 0; s < 4; ++s) {
            float wts[4]; int pix[4];
            sample_wix(p, ph, pw, s, wts, pix);
            #pragma unroll
            for (int i = 0; i < 4; ++i) {
                const size_t cb = (size_t)(p.b * Cc + cq * 4 + i) * HWn;
                acc[i] += wts[0] * feat[cb + pix[0] - p.b * HWn] +
                          wts[1] * feat[cb + pix[1] - p.b * HWn] +
                          wts[2] * feat[cb + pix[2] - p.b * HWn] +
                          wts[3] * feat[cb + pix[3] - p.b * HWn];
            }
        }
        #pragma unroll
        for (int i = 0; i < 4; ++i) sbuf[bin * LSTRIDE + cq * 4 + i] = acc[i];
    }
    __syncthreads();
    const size_t obase = (size_t)n * (Cc * NBIN);
    for (int e = t; e < Cc * NBIN; e += 256) {
        const int c = e / NBIN, bi = e - c * NBIN;
        out[obase + e] = sbuf[bi * LSTRIDE + c];
    }
}

extern "C" void kernel_launch(void* const* d_in, const int* in_sizes, int n_in,
                              void* d_out, int out_size, void* d_ws, size_t ws_size,
                              hipStream_t stream) {
    const float* inputs = (const float*)d_in[0];
    const float* rois   = (const float*)d_in[1];
    float* out = (float*)d_out;

    const size_t need = (size_t)Bc * HWn * Cc * sizeof(unsigned short);
    if (d_ws != nullptr && ws_size >= need) {
        unsigned short* nhwc = (unsigned short*)d_ws;
        dim3 tg(HWn / 64, Cc / 64, Bc);
        transpose_to_bf16_nhwc<<<tg, 256, 0, stream>>>(inputs, nhwc);
        roialign_bf16<<<NROI * 4, 256, 0, stream>>>(nhwc, rois, out);
    } else {
        roialign_nchw<<<NROI, 256, 0, stream>>>(inputs, rois, out);
    }
}